// Round 1
// baseline (1356.382 us; speedup 1.0000x reference)
//
#include <hip/hip_runtime.h>
#include <hip/hip_bf16.h>
#include <cstdint>
#include <cstddef>

#define S_TOK 2048
#define M_DIM 768
#define H_DIM 3072
#define E_NUM 16
#define CAP   256   // 2*S/E

// ---------------------------------------------------------------------------
// Kernel 1: gating — logits = x@wg, softmax, top1/top2 (one wave per token)
// ---------------------------------------------------------------------------
__global__ void gating_kernel(const float* __restrict__ x, const float* __restrict__ wg,
                              int* __restrict__ e1o, int* __restrict__ e2o,
                              float* __restrict__ g1o, float* __restrict__ g2o, int ntok) {
    int gid  = blockIdx.x * blockDim.x + threadIdx.x;
    int tok  = gid >> 6;
    int lane = threadIdx.x & 63;
    if (tok >= ntok) return;
    const float* xr = x + (size_t)tok * M_DIM;
    float acc[E_NUM];
#pragma unroll
    for (int e = 0; e < E_NUM; ++e) acc[e] = 0.f;
    for (int m = lane; m < M_DIM; m += 64) {
        float xv = xr[m];
        const float* wr = wg + (size_t)m * E_NUM;
#pragma unroll
        for (int e = 0; e < E_NUM; ++e) acc[e] += xv * wr[e];
    }
#pragma unroll
    for (int off = 32; off >= 1; off >>= 1) {
#pragma unroll
        for (int e = 0; e < E_NUM; ++e) acc[e] += __shfl_xor(acc[e], off, 64);
    }
    if (lane == 0) {
        float mx = acc[0];
#pragma unroll
        for (int e = 1; e < E_NUM; ++e) mx = fmaxf(mx, acc[e]);
        float p[E_NUM]; float s = 0.f;
#pragma unroll
        for (int e = 0; e < E_NUM; ++e) { p[e] = expf(acc[e] - mx); s += p[e]; }
        float inv = 1.f / s;
        int b1 = 0; float v1 = -1.f;
#pragma unroll
        for (int e = 0; e < E_NUM; ++e) { if (p[e] > v1) { v1 = p[e]; b1 = e; } }
        int b2 = 0; float v2 = -1.f;
#pragma unroll
        for (int e = 0; e < E_NUM; ++e) { if (e != b1 && p[e] > v2) { v2 = p[e]; b2 = e; } }
        e1o[tok] = b1; e2o[tok] = b2;
        g1o[tok] = v1 * inv; g2o[tok] = v2 * inv;
    }
}

// ---------------------------------------------------------------------------
// Kernel 2: assignment — capacity positions via ballot prefix scan.
// One block per group (1024 threads = 16 waves); wave w handles expert w.
// ---------------------------------------------------------------------------
__global__ void assign_kernel(const int* __restrict__ e1a, const int* __restrict__ e2a,
                              const float* __restrict__ g1a, const float* __restrict__ g2a,
                              int* __restrict__ slot1, int* __restrict__ slot2,
                              float* __restrict__ w1, float* __restrict__ w2,
                              int* __restrict__ tfs, int G) {
    int g    = blockIdx.x;
    int tid  = threadIdx.x;
    int w    = tid >> 6;    // expert id for this wave
    int lane = tid & 63;
    __shared__ int cnt1s[E_NUM];

    // init token_for_slot for this group to -1
    for (int i = tid; i < E_NUM * CAP; i += 1024) tfs[(size_t)g * E_NUM * CAP + i] = -1;
    __syncthreads();

    // top-1 scan (exclusive cumsum per expert, drop at capacity)
    {
        int cnt = 0;
        for (int base = 0; base < S_TOK; base += 64) {
            int t = g * S_TOK + base + lane;
            bool pred = (e1a[t] == w);
            unsigned long long bal = __ballot(pred);
            int prefix = __popcll(bal & ((1ull << lane) - 1ull));
            if (pred) {
                int pos = cnt + prefix;
                if (pos < CAP) {
                    slot1[t] = w * CAP + pos;
                    tfs[((size_t)g * E_NUM + w) * CAP + pos] = base + lane;
                } else {
                    slot1[t] = -1;
                }
            }
            cnt += __popcll(bal);
        }
        if (lane == 0) cnt1s[w] = cnt < CAP ? cnt : CAP;
    }
    __syncthreads();
    // top-2 scan, offset by kept top-1 count
    {
        int cnt = cnt1s[w];
        for (int base = 0; base < S_TOK; base += 64) {
            int t = g * S_TOK + base + lane;
            bool pred = (e2a[t] == w);
            unsigned long long bal = __ballot(pred);
            int prefix = __popcll(bal & ((1ull << lane) - 1ull));
            if (pred) {
                int pos = cnt + prefix;
                if (pos < CAP) {
                    slot2[t] = w * CAP + pos;
                    tfs[((size_t)g * E_NUM + w) * CAP + pos] = base + lane;
                } else {
                    slot2[t] = -1;
                }
            }
            cnt += __popcll(bal);
        }
    }
    __syncthreads();
    // normalized combine weights
    for (int t = tid; t < S_TOK; t += 1024) {
        int gt = g * S_TOK + t;
        float a = slot1[gt] >= 0 ? g1a[gt] : 0.f;
        float b = slot2[gt] >= 0 ? g2a[gt] : 0.f;
        float denom = a + b;
        if (!(denom > 0.f)) denom = 1.f;
        w1[gt] = a / denom;
        w2[gt] = b / denom;
    }
}

// ---------------------------------------------------------------------------
// Kernel 3: gemm1 — h[e,g,c,:] = relu( gather(x)[c,:] @ wi[e] )
// 64x64 tile, 256 threads, 4x4 micro, BK=16
// ---------------------------------------------------------------------------
#define BK 16
__global__ __launch_bounds__(256) void gemm1_kernel(const float* __restrict__ x,
                                                    const float* __restrict__ wi,
                                                    const int* __restrict__ tfs,
                                                    float* __restrict__ h, int G) {
    int eg = blockIdx.z;           // e*G + g
    int e  = eg / G, g = eg % G;
    int h0 = blockIdx.x * 64;
    int c0 = blockIdx.y * 64;
    int tid = threadIdx.x;
    __shared__ float As[BK][68];   // pad 68: store bank-2-way-free, read 16B aligned
    __shared__ float Bs[BK][64];
    __shared__ int rowtok[64];
    if (tid < 64) rowtok[tid] = tfs[((size_t)g * E_NUM + e) * CAP + c0 + tid];
    __syncthreads();

    float acc[4][4] = {};
    int tx = tid & 15, ty = tid >> 4;
    const float* wiE = wi + (size_t)e * M_DIM * H_DIM;

    for (int k0 = 0; k0 < M_DIM; k0 += BK) {
        // A tile: As[k][c], gathered rows
        int kk = tid & 15;
        int cr = tid >> 4;
#pragma unroll
        for (int pass = 0; pass < 4; ++pass) {
            int c = pass * 16 + cr;
            int tok = rowtok[c];
            float v = 0.f;
            if (tok >= 0) v = x[((size_t)(g * S_TOK + tok)) * M_DIM + k0 + kk];
            As[kk][c] = v;
        }
        // B tile: Bs[k][hcol]
        int hh = tid & 63;
        int kb = tid >> 6;
#pragma unroll
        for (int pass = 0; pass < 4; ++pass) {
            int kk2 = pass * 4 + kb;
            Bs[kk2][hh] = wiE[(size_t)(k0 + kk2) * H_DIM + h0 + hh];
        }
        __syncthreads();
#pragma unroll
        for (int k = 0; k < BK; ++k) {
            float4 a4 = *(const float4*)&As[k][ty * 4];
            float4 b4 = *(const float4*)&Bs[k][tx * 4];
            float av[4] = {a4.x, a4.y, a4.z, a4.w};
            float bv[4] = {b4.x, b4.y, b4.z, b4.w};
#pragma unroll
            for (int i = 0; i < 4; ++i)
#pragma unroll
                for (int j = 0; j < 4; ++j) acc[i][j] += av[i] * bv[j];
        }
        __syncthreads();
    }
#pragma unroll
    for (int i = 0; i < 4; ++i) {
        float4 o;
        o.x = fmaxf(acc[i][0], 0.f); o.y = fmaxf(acc[i][1], 0.f);
        o.z = fmaxf(acc[i][2], 0.f); o.w = fmaxf(acc[i][3], 0.f);
        size_t idx = ((size_t)eg * CAP + c0 + ty * 4 + i) * H_DIM + h0 + tx * 4;
        *(float4*)&h[idx] = o;
    }
}

// ---------------------------------------------------------------------------
// Kernel 4: gemm2 — eo[g,e,c,:] = h[e,g,c,:] @ wo[e]
// ---------------------------------------------------------------------------
__global__ __launch_bounds__(256) void gemm2_kernel(const float* __restrict__ h,
                                                    const float* __restrict__ wo,
                                                    float* __restrict__ eo, int G) {
    int eg = blockIdx.z;           // e*G + g
    int e  = eg / G, g = eg % G;
    int m0 = blockIdx.x * 64;
    int c0 = blockIdx.y * 64;
    int tid = threadIdx.x;
    __shared__ float As[BK][68];
    __shared__ float Bs[BK][64];

    float acc[4][4] = {};
    int tx = tid & 15, ty = tid >> 4;
    const float* A = h + ((size_t)eg * CAP) * H_DIM;   // [CAP][H]
    const float* B = wo + (size_t)e * H_DIM * M_DIM;   // [H][M]

    for (int k0 = 0; k0 < H_DIM; k0 += BK) {
        int kk = tid & 15;
        int cr = tid >> 4;
#pragma unroll
        for (int pass = 0; pass < 4; ++pass) {
            int c = pass * 16 + cr;
            As[kk][c] = A[(size_t)(c0 + c) * H_DIM + k0 + kk];
        }
        int mm = tid & 63;
        int kb = tid >> 6;
#pragma unroll
        for (int pass = 0; pass < 4; ++pass) {
            int kk2 = pass * 4 + kb;
            Bs[kk2][mm] = B[(size_t)(k0 + kk2) * M_DIM + m0 + mm];
        }
        __syncthreads();
#pragma unroll
        for (int k = 0; k < BK; ++k) {
            float4 a4 = *(const float4*)&As[k][ty * 4];
            float4 b4 = *(const float4*)&Bs[k][tx * 4];
            float av[4] = {a4.x, a4.y, a4.z, a4.w};
            float bv[4] = {b4.x, b4.y, b4.z, b4.w};
#pragma unroll
            for (int i = 0; i < 4; ++i)
#pragma unroll
                for (int j = 0; j < 4; ++j) acc[i][j] += av[i] * bv[j];
        }
        __syncthreads();
    }
    // eo layout: ((g*E + e)*CAP + c)*M + m
#pragma unroll
    for (int i = 0; i < 4; ++i) {
        float4 o;
        o.x = acc[i][0]; o.y = acc[i][1]; o.z = acc[i][2]; o.w = acc[i][3];
        size_t idx = (((size_t)g * E_NUM + e) * CAP + c0 + ty * 4 + i) * M_DIM + m0 + tx * 4;
        *(float4*)&eo[idx] = o;
    }
}

// ---------------------------------------------------------------------------
// Kernel 5: combine — out[t,:] = w1*eo[g,slot1,:] + w2*eo[g,slot2,:]
// ---------------------------------------------------------------------------
__global__ void combine_kernel(const float* __restrict__ eo,
                               const int* __restrict__ slot1, const int* __restrict__ slot2,
                               const float* __restrict__ w1, const float* __restrict__ w2,
                               float* __restrict__ out, int G) {
    int t = blockIdx.x;        // global token
    int g = t / S_TOK;
    int tid = threadIdx.x;
    int s1 = slot1[t], s2 = slot2[t];
    float a = w1[t], b = w2[t];
    const float* base_g = eo + (size_t)g * E_NUM * CAP * M_DIM;
    const float* p1 = base_g + (size_t)(s1 < 0 ? 0 : s1) * M_DIM;
    const float* p2 = base_g + (size_t)(s2 < 0 ? 0 : s2) * M_DIM;
    for (int m = tid; m < M_DIM; m += 256) {
        float v = 0.f;
        if (s1 >= 0) v += a * p1[m];
        if (s2 >= 0) v += b * p2[m];
        out[(size_t)t * M_DIM + m] = v;
    }
}

// ---------------------------------------------------------------------------
extern "C" void kernel_launch(void* const* d_in, const int* in_sizes, int n_in,
                              void* d_out, int out_size, void* d_ws, size_t ws_size,
                              hipStream_t stream) {
    const float* x  = (const float*)d_in[0];
    const float* wg = (const float*)d_in[1];
    const float* wi = (const float*)d_in[2];
    const float* wo = (const float*)d_in[3];
    float* out = (float*)d_out;

    int ntok = in_sizes[0] / M_DIM;   // 4096
    int G = ntok / S_TOK;             // 2

    // workspace carve (all 4-byte elements)
    char* wsp = (char*)d_ws;
    int*   e1    = (int*)wsp;                     wsp += (size_t)ntok * 4;
    int*   e2    = (int*)wsp;                     wsp += (size_t)ntok * 4;
    float* g1    = (float*)wsp;                   wsp += (size_t)ntok * 4;
    float* g2    = (float*)wsp;                   wsp += (size_t)ntok * 4;
    int*   slot1 = (int*)wsp;                     wsp += (size_t)ntok * 4;
    int*   slot2 = (int*)wsp;                     wsp += (size_t)ntok * 4;
    float* w1    = (float*)wsp;                   wsp += (size_t)ntok * 4;
    float* w2    = (float*)wsp;                   wsp += (size_t)ntok * 4;
    int*   tfs   = (int*)wsp;                     wsp += (size_t)G * E_NUM * CAP * 4;
    float* h     = (float*)wsp;                   wsp += (size_t)E_NUM * G * CAP * H_DIM * 4;
    float* eo    = (float*)wsp;                   // G*E*CAP*M floats

    gating_kernel<<<(ntok * 64 + 255) / 256, 256, 0, stream>>>(x, wg, e1, e2, g1, g2, ntok);
    assign_kernel<<<G, 1024, 0, stream>>>(e1, e2, g1, g2, slot1, slot2, w1, w2, tfs, G);
    gemm1_kernel<<<dim3(H_DIM / 64, CAP / 64, E_NUM * G), 256, 0, stream>>>(x, wi, tfs, h, G);
    gemm2_kernel<<<dim3(M_DIM / 64, CAP / 64, E_NUM * G), 256, 0, stream>>>(h, wo, eo, G);
    combine_kernel<<<ntok, 256, 0, stream>>>(eo, slot1, slot2, w1, w2, out, G);
}

// Round 2
// 552.427 us; speedup vs baseline: 2.4553x; 2.4553x over previous
//
#include <hip/hip_runtime.h>
#include <hip/hip_bf16.h>
#include <cstdint>
#include <cstddef>

#define S_TOK 2048
#define M_DIM 768
#define H_DIM 3072
#define E_NUM 16
#define CAP   256   // 2*S/E

using s16x8 = __attribute__((ext_vector_type(8))) short;  // 8 bf16 (4 VGPRs)
using f32x4 = __attribute__((ext_vector_type(4))) float;

__device__ __forceinline__ unsigned short f2bf(float f) {
    unsigned u = __float_as_uint(f);
    unsigned r = 0x7fffu + ((u >> 16) & 1u);
    return (unsigned short)((u + r) >> 16);
}

__device__ __forceinline__ void async16(const void* g, void* l) {
    __builtin_amdgcn_global_load_lds((const __attribute__((address_space(1))) void*)g,
                                     (__attribute__((address_space(3))) void*)l, 16, 0, 0);
}

// ---------------------------------------------------------------------------
// Kernel 1: gating — logits = x@wg, softmax, top1/top2 (one wave per token)
// ---------------------------------------------------------------------------
__global__ void gating_kernel(const float* __restrict__ x, const float* __restrict__ wg,
                              int* __restrict__ e1o, int* __restrict__ e2o,
                              float* __restrict__ g1o, float* __restrict__ g2o, int ntok) {
    int gid  = blockIdx.x * blockDim.x + threadIdx.x;
    int tok  = gid >> 6;
    int lane = threadIdx.x & 63;
    if (tok >= ntok) return;
    const float* xr = x + (size_t)tok * M_DIM;
    float acc[E_NUM];
#pragma unroll
    for (int e = 0; e < E_NUM; ++e) acc[e] = 0.f;
    for (int m = lane; m < M_DIM; m += 64) {
        float xv = xr[m];
        const float* wr = wg + (size_t)m * E_NUM;
#pragma unroll
        for (int e = 0; e < E_NUM; ++e) acc[e] += xv * wr[e];
    }
#pragma unroll
    for (int off = 32; off >= 1; off >>= 1) {
#pragma unroll
        for (int e = 0; e < E_NUM; ++e) acc[e] += __shfl_xor(acc[e], off, 64);
    }
    if (lane == 0) {
        float mx = acc[0];
#pragma unroll
        for (int e = 1; e < E_NUM; ++e) mx = fmaxf(mx, acc[e]);
        float p[E_NUM]; float s = 0.f;
#pragma unroll
        for (int e = 0; e < E_NUM; ++e) { p[e] = expf(acc[e] - mx); s += p[e]; }
        float inv = 1.f / s;
        int b1 = 0; float v1 = -1.f;
#pragma unroll
        for (int e = 0; e < E_NUM; ++e) { if (p[e] > v1) { v1 = p[e]; b1 = e; } }
        int b2 = 0; float v2 = -1.f;
#pragma unroll
        for (int e = 0; e < E_NUM; ++e) { if (e != b1 && p[e] > v2) { v2 = p[e]; b2 = e; } }
        e1o[tok] = b1; e2o[tok] = b2;
        g1o[tok] = v1 * inv; g2o[tok] = v2 * inv;
    }
}

// ---------------------------------------------------------------------------
// Kernel 2: assignment — capacity positions via ballot prefix scan.
// ---------------------------------------------------------------------------
__global__ void assign_kernel(const int* __restrict__ e1a, const int* __restrict__ e2a,
                              const float* __restrict__ g1a, const float* __restrict__ g2a,
                              int* __restrict__ slot1, int* __restrict__ slot2,
                              float* __restrict__ w1, float* __restrict__ w2,
                              int* __restrict__ tfs, int G) {
    int g    = blockIdx.x;
    int tid  = threadIdx.x;
    int w    = tid >> 6;
    int lane = tid & 63;
    __shared__ int cnt1s[E_NUM];

    for (int i = tid; i < E_NUM * CAP; i += 1024) tfs[(size_t)g * E_NUM * CAP + i] = -1;
    __syncthreads();

    {
        int cnt = 0;
        for (int base = 0; base < S_TOK; base += 64) {
            int t = g * S_TOK + base + lane;
            bool pred = (e1a[t] == w);
            unsigned long long bal = __ballot(pred);
            int prefix = __popcll(bal & ((1ull << lane) - 1ull));
            if (pred) {
                int pos = cnt + prefix;
                if (pos < CAP) {
                    slot1[t] = w * CAP + pos;
                    tfs[((size_t)g * E_NUM + w) * CAP + pos] = base + lane;
                } else {
                    slot1[t] = -1;
                }
            }
            cnt += __popcll(bal);
        }
        if (lane == 0) cnt1s[w] = cnt < CAP ? cnt : CAP;
    }
    __syncthreads();
    {
        int cnt = cnt1s[w];
        for (int base = 0; base < S_TOK; base += 64) {
            int t = g * S_TOK + base + lane;
            bool pred = (e2a[t] == w);
            unsigned long long bal = __ballot(pred);
            int prefix = __popcll(bal & ((1ull << lane) - 1ull));
            if (pred) {
                int pos = cnt + prefix;
                if (pos < CAP) {
                    slot2[t] = w * CAP + pos;
                    tfs[((size_t)g * E_NUM + w) * CAP + pos] = base + lane;
                } else {
                    slot2[t] = -1;
                }
            }
            cnt += __popcll(bal);
        }
    }
    __syncthreads();
    for (int t = tid; t < S_TOK; t += 1024) {
        int gt = g * S_TOK + t;
        float a = slot1[gt] >= 0 ? g1a[gt] : 0.f;
        float b = slot2[gt] >= 0 ? g2a[gt] : 0.f;
        float denom = a + b;
        if (!(denom > 0.f)) denom = 1.f;
        w1[gt] = a / denom;
        w2[gt] = b / denom;
    }
}

// ---------------------------------------------------------------------------
// Kernel 3: x fp32 -> bf16, plus one zero row appended at row ntok
// ---------------------------------------------------------------------------
__global__ void convert_x_kernel(const float* __restrict__ x, unsigned short* __restrict__ xb,
                                 int ntok) {
    int i4 = blockIdx.x * blockDim.x + threadIdx.x;
    size_t base = (size_t)i4 * 4;
    size_t n_real = (size_t)ntok * M_DIM;
    size_t n_tot  = (size_t)(ntok + 1) * M_DIM;
    if (base >= n_tot) return;
    ushort4 o;
    if (base < n_real) {
        float4 v = *(const float4*)&x[base];
        o.x = f2bf(v.x); o.y = f2bf(v.y); o.z = f2bf(v.z); o.w = f2bf(v.w);
    } else {
        o.x = o.y = o.z = o.w = 0;
    }
    *(ushort4*)&xb[base] = o;
}

// ---------------------------------------------------------------------------
// Kernel 4: transpose+convert: src [E][R][C] fp32 -> dst [E][C][R] bf16
// grid (C/64, R/64, E), 256 threads
// ---------------------------------------------------------------------------
__global__ __launch_bounds__(256) void transpose_conv_kernel(const float* __restrict__ src,
                                                             unsigned short* __restrict__ dst,
                                                             int R, int C) {
    __shared__ float T[64][65];
    int e  = blockIdx.z;
    int c0 = blockIdx.x * 64;
    int r0 = blockIdx.y * 64;
    int tid = threadIdx.x;
    int lx = tid & 63, ly = tid >> 6;
    const float* S = src + (size_t)e * R * C;
#pragma unroll
    for (int i = 0; i < 16; ++i) {
        int r = i * 4 + ly;
        T[r][lx] = S[(size_t)(r0 + r) * C + c0 + lx];
    }
    __syncthreads();
    unsigned short* D = dst + (size_t)e * C * R;
#pragma unroll
    for (int i = 0; i < 16; ++i) {
        int c = i * 4 + ly;
        D[(size_t)(c0 + c) * R + r0 + lx] = f2bf(T[lx][c]);
    }
}

// ---------------------------------------------------------------------------
// Kernel 5: MFMA GEMM, 128x128 tile, BK=32, global_load_lds staging.
// A: [rows][KLEN] bf16 (optionally gathered via tfs); B: [n][KLEN] bf16.
// GATHER: A = x_bf16 (zero row at index zrow), out = h bf16 with relu.
// else:   A = h + z*CAP*KLEN, out = eo fp32.
// ---------------------------------------------------------------------------
template<int KLEN, bool GATHER>
__global__ __launch_bounds__(256) void mfma_gemm_kernel(
        const unsigned short* __restrict__ A,
        const unsigned short* __restrict__ B,
        const int* __restrict__ tfs,
        void* __restrict__ Out, int G, int N_total) {
    __shared__ unsigned short As[128 * 32];
    __shared__ unsigned short Bs[128 * 32];
    __shared__ int rowtok[128];

    int z  = blockIdx.z;            // e*G + g
    int e  = z / G, g = z % G;
    int n0 = blockIdx.x * 128;
    int c0 = blockIdx.y * 128;
    int tid = threadIdx.x;

    if (GATHER) {
        if (tid < 128) rowtok[tid] = tfs[((size_t)g * E_NUM + e) * CAP + c0 + tid];
        __syncthreads();
    }

    int r4 = tid >> 2, l4 = tid & 3;
    const unsigned short *apt0, *apt1;
    if (GATHER) {
        int t0 = rowtok[r4], t1 = rowtok[64 + r4];
        size_t row0 = (t0 < 0) ? (size_t)(G * S_TOK) : (size_t)(g * S_TOK + t0);
        size_t row1 = (t1 < 0) ? (size_t)(G * S_TOK) : (size_t)(g * S_TOK + t1);
        apt0 = A + row0 * KLEN + l4 * 8;
        apt1 = A + row1 * KLEN + l4 * 8;
    } else {
        apt0 = A + ((size_t)z * CAP + c0 + r4) * KLEN + l4 * 8;
        apt1 = apt0 + (size_t)64 * KLEN;
    }
    const unsigned short* Bexp = B + (size_t)e * N_total * KLEN;
    const unsigned short* bpt0 = Bexp + ((size_t)n0 + r4) * KLEN + l4 * 8;
    const unsigned short* bpt1 = bpt0 + (size_t)64 * KLEN;

    int wv = tid >> 6;
    unsigned short* as0 = &As[(wv * 16) * 32];
    unsigned short* as1 = &As[(64 + wv * 16) * 32];
    unsigned short* bs0 = &Bs[(wv * 16) * 32];
    unsigned short* bs1 = &Bs[(64 + wv * 16) * 32];

    int lane = tid & 63;
    int r = lane & 15, q = lane >> 4;
    int wm = wv & 1, wn = wv >> 1;

    f32x4 acc[4][4];
#pragma unroll
    for (int i = 0; i < 4; ++i)
#pragma unroll
        for (int j = 0; j < 4; ++j) acc[i][j] = (f32x4)(0.f);

    for (int k0 = 0; k0 < KLEN; k0 += 32) {
        async16(apt0, as0);
        async16(apt1, as1);
        async16(bpt0, bs0);
        async16(bpt1, bs1);
        apt0 += 32; apt1 += 32; bpt0 += 32; bpt1 += 32;
        __syncthreads();
        s16x8 af[4], bfr[4];
#pragma unroll
        for (int i = 0; i < 4; ++i)
            af[i] = *(const s16x8*)&As[(wm * 64 + i * 16 + r) * 32 + q * 8];
#pragma unroll
        for (int j = 0; j < 4; ++j)
            bfr[j] = *(const s16x8*)&Bs[(wn * 64 + j * 16 + r) * 32 + q * 8];
#pragma unroll
        for (int i = 0; i < 4; ++i)
#pragma unroll
            for (int j = 0; j < 4; ++j)
                acc[i][j] = __builtin_amdgcn_mfma_f32_16x16x32_bf16(af[i], bfr[j], acc[i][j], 0, 0, 0);
        __syncthreads();
    }

    // epilogue
    if (GATHER) {
        unsigned short* H = (unsigned short*)Out;   // [z][CAP][N_total]
#pragma unroll
        for (int i = 0; i < 4; ++i) {
#pragma unroll
            for (int v = 0; v < 4; ++v) {
                int m_loc = wm * 64 + i * 16 + q * 4 + v;
                unsigned short* row = H + ((size_t)z * CAP + c0 + m_loc) * N_total + n0;
#pragma unroll
                for (int j = 0; j < 4; ++j) {
                    int n_loc = wn * 64 + j * 16 + r;
                    row[n_loc] = f2bf(fmaxf(acc[i][j][v], 0.f));
                }
            }
        }
    } else {
        float* O = (float*)Out;                     // [(g*E+e)][CAP][N_total]
#pragma unroll
        for (int i = 0; i < 4; ++i) {
#pragma unroll
            for (int v = 0; v < 4; ++v) {
                int m_loc = wm * 64 + i * 16 + q * 4 + v;
                float* row = O + (((size_t)g * E_NUM + e) * CAP + c0 + m_loc) * N_total + n0;
#pragma unroll
                for (int j = 0; j < 4; ++j) {
                    int n_loc = wn * 64 + j * 16 + r;
                    row[n_loc] = acc[i][j][v];
                }
            }
        }
    }
}

// ---------------------------------------------------------------------------
// Kernel 6: combine — out[t,:] = w1*eo[g,slot1,:] + w2*eo[g,slot2,:]
// ---------------------------------------------------------------------------
__global__ void combine_kernel(const float* __restrict__ eo,
                               const int* __restrict__ slot1, const int* __restrict__ slot2,
                               const float* __restrict__ w1, const float* __restrict__ w2,
                               float* __restrict__ out, int G) {
    int t = blockIdx.x;
    int g = t / S_TOK;
    int tid = threadIdx.x;
    int s1 = slot1[t], s2 = slot2[t];
    float a = w1[t], b = w2[t];
    const float* base_g = eo + (size_t)g * E_NUM * CAP * M_DIM;
    const float* p1 = base_g + (size_t)(s1 < 0 ? 0 : s1) * M_DIM;
    const float* p2 = base_g + (size_t)(s2 < 0 ? 0 : s2) * M_DIM;
    for (int m = tid; m < M_DIM; m += 256) {
        float v = 0.f;
        if (s1 >= 0) v += a * p1[m];
        if (s2 >= 0) v += b * p2[m];
        out[(size_t)t * M_DIM + m] = v;
    }
}

// ---------------------------------------------------------------------------
extern "C" void kernel_launch(void* const* d_in, const int* in_sizes, int n_in,
                              void* d_out, int out_size, void* d_ws, size_t ws_size,
                              hipStream_t stream) {
    const float* x  = (const float*)d_in[0];
    const float* wg = (const float*)d_in[1];
    const float* wi = (const float*)d_in[2];
    const float* wo = (const float*)d_in[3];
    float* out = (float*)d_out;

    int ntok = in_sizes[0] / M_DIM;   // 4096
    int G = ntok / S_TOK;             // 2

    // workspace carve (256B aligned chunks)
    char* wsp = (char*)d_ws;
    auto carve = [&](size_t bytes) {
        void* p = (void*)wsp;
        wsp += (bytes + 255) & ~(size_t)255;
        return p;
    };
    int*   e1    = (int*)carve((size_t)ntok * 4);
    int*   e2    = (int*)carve((size_t)ntok * 4);
    float* g1    = (float*)carve((size_t)ntok * 4);
    float* g2    = (float*)carve((size_t)ntok * 4);
    int*   slot1 = (int*)carve((size_t)ntok * 4);
    int*   slot2 = (int*)carve((size_t)ntok * 4);
    float* w1    = (float*)carve((size_t)ntok * 4);
    float* w2    = (float*)carve((size_t)ntok * 4);
    int*   tfs   = (int*)carve((size_t)G * E_NUM * CAP * 4);
    unsigned short* xb  = (unsigned short*)carve((size_t)(ntok + 1) * M_DIM * 2);
    unsigned short* wiT = (unsigned short*)carve((size_t)E_NUM * H_DIM * M_DIM * 2);
    unsigned short* woT = (unsigned short*)carve((size_t)E_NUM * M_DIM * H_DIM * 2);
    unsigned short* h   = (unsigned short*)carve((size_t)E_NUM * G * CAP * H_DIM * 2);
    float* eo = (float*)carve((size_t)G * E_NUM * CAP * M_DIM * 4);

    gating_kernel<<<(ntok * 64 + 255) / 256, 256, 0, stream>>>(x, wg, e1, e2, g1, g2, ntok);
    assign_kernel<<<G, 1024, 0, stream>>>(e1, e2, g1, g2, slot1, slot2, w1, w2, tfs, G);

    int nx4 = ((ntok + 1) * M_DIM) / 4;
    convert_x_kernel<<<(nx4 + 255) / 256, 256, 0, stream>>>(x, xb, ntok);
    // wi [E][M][H] -> wiT [E][H][M]
    transpose_conv_kernel<<<dim3(H_DIM / 64, M_DIM / 64, E_NUM), 256, 0, stream>>>(wi, wiT, M_DIM, H_DIM);
    // wo [E][H][M] -> woT [E][M][H]
    transpose_conv_kernel<<<dim3(M_DIM / 64, H_DIM / 64, E_NUM), 256, 0, stream>>>(wo, woT, H_DIM, M_DIM);

    // gemm1: h[z][CAP][H] = relu(gather(xb) @ wiT^T), K=768
    mfma_gemm_kernel<M_DIM, true><<<dim3(H_DIM / 128, CAP / 128, E_NUM * G), 256, 0, stream>>>(
        xb, wiT, tfs, h, G, H_DIM);
    // gemm2: eo[(g*E+e)][CAP][M] = h @ woT^T, K=3072
    mfma_gemm_kernel<H_DIM, false><<<dim3(M_DIM / 128, CAP / 128, E_NUM * G), 256, 0, stream>>>(
        h, woT, tfs, eo, G, M_DIM);

    combine_kernel<<<ntok, 256, 0, stream>>>(eo, slot1, slot2, w1, w2, out, G);
}